// Round 1
// baseline (26.028 us; speedup 1.0000x reference)
//
#include <hip/hip_runtime.h>
#include <math.h>

// Problem constants (from reference setup_inputs): B=32, H=W=1024.
constexpr int B = 32;
constexpr int H = 1024;
constexpr int W = 1024;
constexpr int BPB = 64;       // blocks per batch image
constexpr int NTHREADS = 256; // 4 waves; 256 threads * float4 = 1024 floats = one row

// Kernel 1: per-block partial sums of -log(1 - p + eps) over "outside" pixels.
// Grid = B * BPB blocks. Block (b, blk) handles rows y = blk, blk+BPB, ...
// Each thread loads one float4 per row (fully coalesced). Waves whose 256-col
// span is entirely inside the bbox skip the load+compute (wave-uniform branch).
__global__ __launch_bounds__(NTHREADS)
void partial_kernel(const float* __restrict__ pred,
                    const float* __restrict__ bboxes,
                    float* __restrict__ ws) {
    const int b   = blockIdx.x / BPB;
    const int blk = blockIdx.x % BPB;

    // bbox -> integer pixel bounds, exactly matching the reference:
    // x1 = max(floor(bx*W),0); x2 = min(floor(bx2*W),W); same for y.
    const float bx1 = bboxes[b * 4 + 0];
    const float by1 = bboxes[b * 4 + 1];
    const float bx2 = bboxes[b * 4 + 2];
    const float by2 = bboxes[b * 4 + 3];
    const int x1 = max((int)floorf(bx1 * (float)W), 0);
    const int y1 = max((int)floorf(by1 * (float)H), 0);
    const int x2 = min((int)floorf(bx2 * (float)W), W);
    const int y2 = min((int)floorf(by2 * (float)H), H);

    const int tid  = threadIdx.x;
    const int x0   = tid * 4;          // this thread's starting column
    const int wave = tid >> 6;         // 0..3
    const int wx0  = wave * 256;       // wave's column span start
    const float* base = pred + (size_t)b * H * W;

    float acc = 0.0f;
    for (int y = blk; y < H; y += BPB) {
        const bool yin = (y >= y1) && (y < y2);
        // wave-uniform skip: whole 256-column span inside the bbox
        if (yin && (wx0 >= x1) && (wx0 + 256 <= x2)) continue;

        const float4 v = *reinterpret_cast<const float4*>(base + (size_t)y * W + x0);
        const float pv[4] = {v.x, v.y, v.z, v.w};
#pragma unroll
        for (int j = 0; j < 4; ++j) {
            const int x = x0 + j;
            const bool inside = yin && (x >= x1) && (x < x2);
            if (!inside) {
                acc -= __logf(1.0f - pv[j] + 1e-7f);
            }
        }
    }

    // wave reduction (width 64), then cross-wave via LDS
    for (int off = 32; off > 0; off >>= 1)
        acc += __shfl_down(acc, off, 64);
    __shared__ float s[NTHREADS / 64];
    if ((tid & 63) == 0) s[wave] = acc;
    __syncthreads();
    if (tid == 0)
        ws[(size_t)b * BPB + blk] = s[0] + s[1] + s[2] + s[3];
}

// Kernel 2: one wave. Lane t < B sums its batch's BPB partials, computes the
// outside-pixel count analytically, normalizes, then a wave reduction averages
// across batches.
__global__ __launch_bounds__(64)
void finalize_kernel(const float* __restrict__ ws,
                     const float* __restrict__ bboxes,
                     float* __restrict__ out) {
    const int t = threadIdx.x;
    float per = 0.0f;
    if (t < B) {
        float s = 0.0f;
        for (int i = 0; i < BPB; ++i) s += ws[t * BPB + i];
        const int x1 = max((int)floorf(bboxes[t * 4 + 0] * (float)W), 0);
        const int y1 = max((int)floorf(bboxes[t * 4 + 1] * (float)H), 0);
        const int x2 = min((int)floorf(bboxes[t * 4 + 2] * (float)W), W);
        const int y2 = min((int)floorf(bboxes[t * 4 + 3] * (float)H), H);
        const float area = (float)(max(0, y2 - y1)) * (float)(max(0, x2 - x1));
        const float cnt  = (float)(H * W) - area;
        per = (cnt > 0.0f) ? (s / fmaxf(cnt, 1.0f)) : 0.0f;
    }
    for (int off = 32; off > 0; off >>= 1)
        per += __shfl_down(per, off, 64);
    if (t == 0) out[0] = per / (float)B;
}

extern "C" void kernel_launch(void* const* d_in, const int* in_sizes, int n_in,
                              void* d_out, int out_size, void* d_ws, size_t ws_size,
                              hipStream_t stream) {
    const float* pred   = (const float*)d_in[0];  // (B,1,H,W) f32
    const float* bboxes = (const float*)d_in[1];  // (B,4) f32
    float* out = (float*)d_out;                   // scalar f32
    float* ws  = (float*)d_ws;                    // B*BPB partials (8 KB)

    partial_kernel<<<B * BPB, NTHREADS, 0, stream>>>(pred, bboxes, ws);
    finalize_kernel<<<1, 64, 0, stream>>>(ws, bboxes, out);
}

// Round 2
// 23.191 us; speedup vs baseline: 1.1223x; 1.1223x over previous
//
#include <hip/hip_runtime.h>
#include <math.h>

// Problem constants (from reference setup_inputs): B=32, H=W=1024.
constexpr int B = 32;
constexpr int H = 1024;
constexpr int W = 1024;
constexpr int BPB = 64;       // blocks per batch image
constexpr int NTHREADS = 256; // 256 threads * float4 = 1024 floats = one row

// Kernel 1: per-block partial sums of -log(1 - p + eps) over "outside" pixels.
// Grid = B * BPB blocks. Block (b, blk) handles rows y = blk, blk+BPB, ...
// For rows outside [y1,y2): all 256 threads load one float4 (full row).
// For rows inside  [y1,y2): loads are COMPACTED to the outside column ranges:
//   threads [0, nL)        -> float4 index i           (left segment, [0, ceil(x1/4)))
//   threads [nL, nAct)     -> float4 index rS + (i-nL) (right segment, [floor(x2/4), 256))
//   threads [nAct, 256)    -> skip (fully-idle waves branch out via execz)
// Boundary float4s straddling x1/x2 are handled by the per-element mask.
__global__ __launch_bounds__(NTHREADS)
void partial_kernel(const float* __restrict__ pred,
                    const float* __restrict__ bboxes,
                    float* __restrict__ ws) {
    const int b   = blockIdx.x / BPB;
    const int blk = blockIdx.x % BPB;

    // bbox -> integer pixel bounds, exactly matching the reference.
    const int x1 = max((int)floorf(bboxes[b * 4 + 0] * (float)W), 0);
    const int y1 = max((int)floorf(bboxes[b * 4 + 1] * (float)H), 0);
    const int x2 = min((int)floorf(bboxes[b * 4 + 2] * (float)W), W);
    const int y2 = min((int)floorf(bboxes[b * 4 + 3] * (float)H), H);

    const int nL   = (x1 + 3) >> 2;   // left-segment float4 count
    const int rS   = x2 >> 2;         // right-segment first float4 index
    const int nAct = nL + (256 - rS); // active threads on inside rows

    const int tid = threadIdx.x;
    const float* base = pred + (size_t)b * H * W;

    float acc = 0.0f;
    for (int y = blk; y < H; y += BPB) {
        const bool yin = (y >= y1) && (y < y2);
        int c4;
        if (yin) {
            if (tid < nL)        c4 = tid;
            else if (tid < nAct) c4 = rS + (tid - nL);
            else continue;            // whole idle waves skip via execz
        } else {
            c4 = tid;
        }

        const float4 v = *reinterpret_cast<const float4*>(base + (size_t)y * W + (c4 << 2));
        const float pv[4] = {v.x, v.y, v.z, v.w};
#pragma unroll
        for (int j = 0; j < 4; ++j) {
            const int x = (c4 << 2) + j;
            const bool inside = yin && (x >= x1) && (x < x2);
            if (!inside) {
                acc -= __logf(1.0f - pv[j] + 1e-7f);
            }
        }
    }

    // wave reduction (width 64), then cross-wave via LDS
    for (int off = 32; off > 0; off >>= 1)
        acc += __shfl_down(acc, off, 64);
    __shared__ float s[NTHREADS / 64];
    const int wave = tid >> 6;
    if ((tid & 63) == 0) s[wave] = acc;
    __syncthreads();
    if (tid == 0)
        ws[(size_t)b * BPB + blk] = s[0] + s[1] + s[2] + s[3];
}

// Kernel 2: one wave. Lane t < B sums its batch's BPB partials, computes the
// outside-pixel count analytically, normalizes, then wave-reduces the mean.
__global__ __launch_bounds__(64)
void finalize_kernel(const float* __restrict__ ws,
                     const float* __restrict__ bboxes,
                     float* __restrict__ out) {
    const int t = threadIdx.x;
    float per = 0.0f;
    if (t < B) {
        float s = 0.0f;
        for (int i = 0; i < BPB; ++i) s += ws[t * BPB + i];
        const int x1 = max((int)floorf(bboxes[t * 4 + 0] * (float)W), 0);
        const int y1 = max((int)floorf(bboxes[t * 4 + 1] * (float)H), 0);
        const int x2 = min((int)floorf(bboxes[t * 4 + 2] * (float)W), W);
        const int y2 = min((int)floorf(bboxes[t * 4 + 3] * (float)H), H);
        const float area = (float)(max(0, y2 - y1)) * (float)(max(0, x2 - x1));
        const float cnt  = (float)(H * W) - area;
        per = (cnt > 0.0f) ? (s / fmaxf(cnt, 1.0f)) : 0.0f;
    }
    for (int off = 32; off > 0; off >>= 1)
        per += __shfl_down(per, off, 64);
    if (t == 0) out[0] = per / (float)B;
}

extern "C" void kernel_launch(void* const* d_in, const int* in_sizes, int n_in,
                              void* d_out, int out_size, void* d_ws, size_t ws_size,
                              hipStream_t stream) {
    const float* pred   = (const float*)d_in[0];  // (B,1,H,W) f32
    const float* bboxes = (const float*)d_in[1];  // (B,4) f32
    float* out = (float*)d_out;                   // scalar f32
    float* ws  = (float*)d_ws;                    // B*BPB partials (8 KB)

    partial_kernel<<<B * BPB, NTHREADS, 0, stream>>>(pred, bboxes, ws);
    finalize_kernel<<<1, 64, 0, stream>>>(ws, bboxes, out);
}